// Round 1
// baseline (954.757 us; speedup 1.0000x reference)
//
#include <hip/hip_runtime.h>
#include <hip/hip_bf16.h>

// Problem constants (BasicRecurrentLayer): B=64, T=1024, F=128, U=256
constexpr int B = 64;
constexpr int T = 1024;
constexpr int F = 128;
constexpr int U = 256;
constexpr int CH = 8;       // rnn: steps per h-prefetch/out-flush chunk

typedef float f32x2 __attribute__((ext_vector_type(2)));

// ---------------------------------------------------------------------------
// h storage helpers (fp32 if workspace fits 64 MB, else bf16 = 32 MB)
// ---------------------------------------------------------------------------
__device__ __forceinline__ float toF32(float v) { return v; }
__device__ __forceinline__ float toF32(__hip_bfloat16 v) { return __bfloat162float(v); }

__device__ __forceinline__ void store8(float* p, const float* a) {
    ((float4*)p)[0] = make_float4(a[0], a[1], a[2], a[3]);
    ((float4*)p)[1] = make_float4(a[4], a[5], a[6], a[7]);
}
__device__ __forceinline__ void store8(__hip_bfloat16* p, const float* a) {
    unsigned int v[4];
    #pragma unroll
    for (int i = 0; i < 4; ++i) {
        __hip_bfloat16 lo = __float2bfloat16(a[2 * i]);
        __hip_bfloat16 hi = __float2bfloat16(a[2 * i + 1]);
        unsigned short lob = *(unsigned short*)&lo;
        unsigned short hib = *(unsigned short*)&hi;
        v[i] = (unsigned int)lob | ((unsigned int)hib << 16);
    }
    ((uint4*)p)[0] = make_uint4(v[0], v[1], v[2], v[3]);
}

__device__ __forceinline__ float rdlane(float v, int l) {
    return __uint_as_float(__builtin_amdgcn_readlane(__float_as_uint(v), l));
}

// Exact identity tanh(x) = 1 - 2/(1+e^{2x}); e^{2x} = exp2(x*2*log2(e)).
// v_exp_f32 + v_rcp_f32, ~1e-6 abs err, correct saturation at +-1, no branches.
__device__ __forceinline__ float tanh_fast(float x) {
    float e = __builtin_amdgcn_exp2f(x * 2.885390081777927f);
    float r = __builtin_amdgcn_rcpf(1.0f + e);
    return fmaf(-2.0f, r, 1.0f);
}

// lgkmcnt(0) only (vmcnt=63, expcnt=7 -> no wait): 0xC07F. Raw barrier that
// does NOT drain vmcnt, so h-prefetch / out-stores stay in flight across it.
__device__ __forceinline__ void lds_barrier() {
    __builtin_amdgcn_s_waitcnt(0xC07F);
    asm volatile("" ::: "memory");
    __builtin_amdgcn_s_barrier();
    asm volatile("" ::: "memory");
}

// Load one k4-group (4 consecutive f-rows) of R for 8 u-columns as f32x2
// pairs: r01[j] = {R[g4+0][u0+j], R[g4+1][u0+j]}, r23[j] = {R[g4+2][u0+j],
// R[g4+3][u0+j]}. Wave-uniform -> scalar loads; pairs feed v_pk_fma_f32.
__device__ __forceinline__ void loadR(const float* Rp, int g,
                                      f32x2* r01, f32x2* r23) {
    #pragma unroll
    for (int j = 0; j < 8; ++j) {
        f32x2 t0 = {Rp[(size_t)(g * 4 + 0) * U + j], Rp[(size_t)(g * 4 + 1) * U + j]};
        f32x2 t1 = {Rp[(size_t)(g * 4 + 2) * U + j], Rp[(size_t)(g * 4 + 3) * U + j]};
        r01[j] = t0;
        r23[j] = t1;
    }
}

// ---------------------------------------------------------------------------
// Kernel 1: projection  h[t, b, u] = sum_f inputs[b, t, f] * R[f, u]
// Grid (T/64, U/64, B), 512 threads (8 waves). lane = t-row r; wave owns 8 u.
// A-tile (64x128 fp32, 32 KB) in LDS, XOR-swizzled float4 slots (conflict-
// free b128 read+write). R in SGPR pairs, ping-pong prefetched one k4-group
// ahead. Inner loop pairs k's into v_pk_fma_f32 (2 FMA/issue): per-thread
// FMA issue 1024 -> 512. Horizontal .x+.y add once at the end.
// ---------------------------------------------------------------------------
template <typename HT>
__global__ __launch_bounds__(512, 2) void proj_kernel(
    const float* __restrict__ in,   // [B, T, F]
    const float* __restrict__ Rm,   // [F, U]
    HT* __restrict__ h)             // [T, B, U]
{
    const int t0   = blockIdx.x * 64;
    const int u0b  = blockIdx.y * 64;
    const int b    = blockIdx.z;
    const int tid  = threadIdx.x;
    const int lane = tid & 63;      // = r (t-row within tile)
    const int wv   = tid >> 6;      // 0..7
    const int u0   = __builtin_amdgcn_readfirstlane(u0b + wv * 8);

    __shared__ float4 a4[64 * 32];  // 32 KB, swizzled

    const float4* src = (const float4*)(in + ((size_t)b * T + t0) * F);
    #pragma unroll
    for (int it = 0; it < 4; ++it) {
        int f  = tid + it * 512;        // 0..2047 coalesced
        int r  = f >> 5;
        int k4 = f & 31;
        a4[(r << 5) | (k4 ^ (r & 31))] = src[f];
    }
    __syncthreads();

    const float* Rp = Rm + u0;      // wave-uniform -> scalar loads
    f32x2 acc2[8];
    #pragma unroll
    for (int j = 0; j < 8; ++j) { f32x2 z = {0.f, 0.f}; acc2[j] = z; }

    f32x2 ra01[8], ra23[8], rb01[8], rb23[8];   // uniform ping-pong R buffers
    loadR(Rp, 0, ra01, ra23);

    const int r = lane;
    #pragma unroll
    for (int k4 = 0; k4 < 32; k4 += 2) {
        // prefetch k4+1 into rb
        loadR(Rp, k4 + 1, rb01, rb23);

        float4 av = a4[(r << 5) | (k4 ^ (r & 31))];
        {
            f32x2 lo = {av.x, av.y};
            f32x2 hi = {av.z, av.w};
            #pragma unroll
            for (int j = 0; j < 8; ++j) {
                acc2[j] = __builtin_elementwise_fma(lo, ra01[j], acc2[j]);
                acc2[j] = __builtin_elementwise_fma(hi, ra23[j], acc2[j]);
            }
        }

        // prefetch k4+2 into ra
        if (k4 + 2 < 32) loadR(Rp, k4 + 2, ra01, ra23);

        float4 av2 = a4[(r << 5) | ((k4 + 1) ^ (r & 31))];
        {
            f32x2 lo = {av2.x, av2.y};
            f32x2 hi = {av2.z, av2.w};
            #pragma unroll
            for (int j = 0; j < 8; ++j) {
                acc2[j] = __builtin_elementwise_fma(lo, rb01[j], acc2[j]);
                acc2[j] = __builtin_elementwise_fma(hi, rb23[j], acc2[j]);
            }
        }
    }

    float accf[8];
    #pragma unroll
    for (int j = 0; j < 8; ++j) accf[j] = acc2[j].x + acc2[j].y;

    HT* hp = h + ((size_t)(t0 + r) * B + b) * U + u0;
    store8(hp, accf);
}

// ---------------------------------------------------------------------------
// Kernel 2: recurrence. Grid 64 (one WG per batch row), 512 threads = 8 waves.
// Wave wv owns k-range [32wv, 32wv+32) AND reduces u' range [32wv, 32wv+32).
// Lane l owns u' columns {4l..4l+3} for the partial GEMV, held as two f32x2
// accumulators so the inner product issues as v_pk_fma_f32 (2 FMA/slot):
//   wA[kk] = {W[32wv+kk][4l+0], W[32wv+kk][4l+1]}, wB likewise for +2/+3.
// Per step: 32 v_readlane (k-broadcast, SGPRs) + 64 v_pk_fma (was 128 v_fma),
// 1 ds_write_b128 of partials, ONE raw barrier, 8 ds_read_b32 tree-reduced
// partials + tanh. h is pre-biased (hc[i] = h + bias) at chunk load to keep
// one dependent add off the post-barrier critical path. The reduced value tv
// sits in this wave's own lanes 0..31 — it IS next step's readlane source, so
// no state write-back and no second barrier. Partials double-buffered (i&1).
// ---------------------------------------------------------------------------
template <typename HT>
__global__ __launch_bounds__(512, 2) void rnn_kernel(
    const HT* __restrict__ h,        // [T, B, U]
    const float* __restrict__ Wm,    // [U, U]
    const float* __restrict__ bias,  // [U]
    const float* __restrict__ x0,    // [U]
    float* __restrict__ out)         // [T, B, U]
{
    const int b    = blockIdx.x;
    const int tid  = threadIdx.x;
    const int l    = tid & 63;
    const int wv   = tid >> 6;       // 0..7
    const int k0   = wv << 5;        // wave's k-range / u'-reduction base

    __shared__ float p[2][8][256];   // 16 KB partials, double-buffered

    // W columns as f32x2 pairs: wA[kk] = W[k0+kk][4l+{0,1}], wB = [4l+{2,3}].
    f32x2 wA[32], wB[32];
    {
        const float* wp = Wm + (size_t)k0 * U + 4 * l;
        #pragma unroll
        for (int kk = 0; kk < 32; ++kk) {
            float4 v = *(const float4*)(wp + (size_t)kk * U);
            f32x2 t0 = {v.x, v.y};
            f32x2 t1 = {v.z, v.w};
            wA[kk] = t0;
            wB[kk] = t1;
        }
    }

    const bool act = (l < 32);
    const int  u   = k0 + (l & 31);  // dup for lanes 32..63 (harmless)
    const float bv = bias[u];

    float tv = x0[u];                // s_new[k0 + (l&31)] lives here each step

    const size_t sT = (size_t)B * U;
    const HT* hp = h + (size_t)b * U + u;
    float* op = out + (size_t)b * U + u;

    float hc[CH], hn[CH], ob[CH];
    #pragma unroll
    for (int i = 0; i < CH; ++i) hc[i] = toF32(hp[(size_t)i * sT]) + bv;

    for (int tc = 0; tc < T; tc += CH) {
        // prefetch next chunk's h (not drained at raw barriers)
        if (tc + CH < T) {
            #pragma unroll
            for (int i = 0; i < CH; ++i)
                hn[i] = toF32(hp[(size_t)(tc + CH + i) * sT]);
        }
        // flush previous chunk's outputs
        if (tc > 0 && act) {
            #pragma unroll
            for (int i = 0; i < CH; ++i)
                op[(size_t)(tc - CH + i) * sT] = ob[i];
        }

        #pragma unroll
        for (int i = 0; i < CH; ++i) {
            // broadcast this wave's 32 state values into SGPRs
            float sb[32];
            #pragma unroll
            for (int kk = 0; kk < 32; ++kk) sb[kk] = rdlane(tv, kk);

            f32x2 aA = {0.f, 0.f};
            f32x2 aB = {0.f, 0.f};
            #pragma unroll
            for (int kk = 0; kk < 32; ++kk) {
                f32x2 sv = {sb[kk], sb[kk]};
                aA = __builtin_elementwise_fma(sv, wA[kk], aA);
                aB = __builtin_elementwise_fma(sv, wB[kk], aB);
            }
            *(float4*)&p[i & 1][wv][4 * l] = make_float4(aA.x, aA.y, aB.x, aB.y);

            lds_barrier();           // ONE barrier per step (lgkm only)

            // tree-reduce 8 partials for u' = k0 + (l&31); lanes 32..63
            // duplicate (same-address LDS reads broadcast — no conflict)
            const float* pb = &p[i & 1][0][u];
            float q0 = pb[0 * 256], q1 = pb[1 * 256];
            float q2 = pb[2 * 256], q3 = pb[3 * 256];
            float q4 = pb[4 * 256], q5 = pb[5 * 256];
            float q6 = pb[6 * 256], q7 = pb[7 * 256];
            float red = ((q0 + q1) + (q2 + q3)) + ((q4 + q5) + (q6 + q7));

            float val = tanh_fast(red + hc[i]);   // hc pre-biased
            ob[i] = val;
            tv = val;                // next step's readlane source
        }

        if (tc + CH < T) {
            #pragma unroll
            for (int i = 0; i < CH; ++i) hc[i] = hn[i] + bv;
        }
    }

    if (act) {
        #pragma unroll
        for (int i = 0; i < CH; ++i)
            op[(size_t)(T - CH + i) * sT] = ob[i];
    }
}

// ---------------------------------------------------------------------------
extern "C" void kernel_launch(void* const* d_in, const int* in_sizes, int n_in,
                              void* d_out, int out_size, void* d_ws, size_t ws_size,
                              hipStream_t stream) {
    const float* in   = (const float*)d_in[0];  // [B, T, F]
    const float* Rm   = (const float*)d_in[1];  // [F, U]
    const float* Wm   = (const float*)d_in[2];  // [U, U]
    const float* bias = (const float*)d_in[3];  // [U]
    const float* x0   = (const float*)d_in[4];  // [U]
    float* out = (float*)d_out;                 // [T, B, U]

    const size_t hElems = (size_t)T * B * U;
    dim3 pgrid(T / 64, U / 64, B);

    if (ws_size >= hElems * sizeof(float)) {
        float* h = (float*)d_ws;
        proj_kernel<float><<<pgrid, 512, 0, stream>>>(in, Rm, h);
        rnn_kernel<float><<<dim3(B), 512, 0, stream>>>(h, Wm, bias, x0, out);
    } else {
        __hip_bfloat16* h = (__hip_bfloat16*)d_ws;
        proj_kernel<__hip_bfloat16><<<pgrid, 512, 0, stream>>>(in, Rm, h);
        rnn_kernel<__hip_bfloat16><<<dim3(B), 512, 0, stream>>>(h, Wm, bias, x0, out);
    }
}

// Round 4
// 722.522 us; speedup vs baseline: 1.3214x; 1.3214x over previous
//
#include <hip/hip_runtime.h>
#include <hip/hip_bf16.h>

// Problem constants (BasicRecurrentLayer): B=64, T=1024, F=128, U=256
constexpr int B = 64;
constexpr int T = 1024;
constexpr int F = 128;
constexpr int U = 256;
constexpr int CH = 8;       // rnn: steps per h-prefetch/out-flush chunk

// __fp16 (not _Float16): matches the exact type of clang's amdgcn builtins
// (cvt_pkrtz / fdot2) so no implicit-conversion errors (round-2 fail).
typedef __fp16 h2 __attribute__((ext_vector_type(2)));

// ---------------------------------------------------------------------------
// h storage helpers (fp32 if workspace fits 64 MB, else bf16 = 32 MB)
// ---------------------------------------------------------------------------
__device__ __forceinline__ float toF32(float v) { return v; }
__device__ __forceinline__ float toF32(__hip_bfloat16 v) { return __bfloat162float(v); }

__device__ __forceinline__ void store8(float* p, const float* a) {
    ((float4*)p)[0] = make_float4(a[0], a[1], a[2], a[3]);
    ((float4*)p)[1] = make_float4(a[4], a[5], a[6], a[7]);
}
__device__ __forceinline__ void store8(__hip_bfloat16* p, const float* a) {
    unsigned int v[4];
    #pragma unroll
    for (int i = 0; i < 4; ++i) {
        __hip_bfloat16 lo = __float2bfloat16(a[2 * i]);
        __hip_bfloat16 hi = __float2bfloat16(a[2 * i + 1]);
        unsigned short lob = *(unsigned short*)&lo;
        unsigned short hib = *(unsigned short*)&hi;
        v[i] = (unsigned int)lob | ((unsigned int)hib << 16);
    }
    ((uint4*)p)[0] = make_uint4(v[0], v[1], v[2], v[3]);
}

__device__ __forceinline__ unsigned int h2bits(h2 v) {
    union { h2 h; unsigned int u; } c; c.h = v; return c.u;
}
__device__ __forceinline__ h2 bits2h(unsigned int u) {
    union { unsigned int u; h2 h; } c; c.u = u; return c.h;
}

// RNE pack: two v_cvt_f16_f32 (default round-nearest-even) + v_pack_b32_f16.
// NOT cvt_pkrtz — RTZ's toward-zero bias accumulated coherently over the
// T=1024 orthogonal-W recurrence and blew the absmax budget (round 3).
__device__ __forceinline__ h2 pk_rne(float a, float b) {
    h2 v; v.x = (__fp16)a; v.y = (__fp16)b; return v;
}

// v_dot2_f32_f16: 2-MAC/lane/cy dot with f32 accumulate.
__device__ __forceinline__ float fdot2(h2 a, h2 b, float c) {
#if __has_builtin(__builtin_amdgcn_fdot2)
    return __builtin_amdgcn_fdot2(a, b, c, false);
#else
    asm("v_dot2_f32_f16 %0, %1, %2, %0" : "+v"(c) : "v"(a), "v"(b));
    return c;
#endif
}

// Exact identity tanh(x) = 1 - 2/(1+e^{2x}); e^{2x} = exp2(x*2*log2(e)).
// v_exp_f32 + v_rcp_f32, ~1e-6 abs err, correct saturation at +-1, no branches.
__device__ __forceinline__ float tanh_fast(float x) {
    float e = __builtin_amdgcn_exp2f(x * 2.885390081777927f);
    float r = __builtin_amdgcn_rcpf(1.0f + e);
    return fmaf(-2.0f, r, 1.0f);
}

// lgkmcnt(0) only (vmcnt=63, expcnt=7 -> no wait): 0xC07F. Raw barrier that
// does NOT drain vmcnt, so h-prefetch / out-stores stay in flight across it.
__device__ __forceinline__ void lds_barrier() {
    __builtin_amdgcn_s_waitcnt(0xC07F);
    asm volatile("" ::: "memory");
    __builtin_amdgcn_s_barrier();
    asm volatile("" ::: "memory");
}

// ---------------------------------------------------------------------------
// Kernel 1: projection  h[t, b, u] = sum_f inputs[b, t, f] * R[f, u]
// Grid (T/64, U/64, B), 512 threads (8 waves). lane = t-row r; wave owns 8 u.
// A-tile (64x128 fp32, 32 KB) in LDS, XOR-swizzled float4 slots (conflict-
// free b128 read+write). R comes in as wave-uniform scalar loads (SGPRs),
// ping-pong prefetched one k4-group ahead to hide s_load latency.
// (Round-0 version verbatim — the f32x2 variant broke SGPR-uniformity and
//  regressed 3.6x.)
// ---------------------------------------------------------------------------
template <typename HT>
__global__ __launch_bounds__(512, 2) void proj_kernel(
    const float* __restrict__ in,   // [B, T, F]
    const float* __restrict__ Rm,   // [F, U]
    HT* __restrict__ h)             // [T, B, U]
{
    const int t0   = blockIdx.x * 64;
    const int u0b  = blockIdx.y * 64;
    const int b    = blockIdx.z;
    const int tid  = threadIdx.x;
    const int lane = tid & 63;      // = r (t-row within tile)
    const int wv   = tid >> 6;      // 0..7
    const int u0   = __builtin_amdgcn_readfirstlane(u0b + wv * 8);

    __shared__ float4 a4[64 * 32];  // 32 KB, swizzled

    const float4* src = (const float4*)(in + ((size_t)b * T + t0) * F);
    #pragma unroll
    for (int it = 0; it < 4; ++it) {
        int f  = tid + it * 512;        // 0..2047 coalesced
        int r  = f >> 5;
        int k4 = f & 31;
        a4[(r << 5) | (k4 ^ (r & 31))] = src[f];
    }
    __syncthreads();

    const float* Rp = Rm + u0;      // wave-uniform -> scalar loads
    float acc[8];
    #pragma unroll
    for (int j = 0; j < 8; ++j) acc[j] = 0.f;

    float ra[32], rb[32];           // uniform (SGPR) ping-pong R buffers
    #pragma unroll
    for (int kk = 0; kk < 4; ++kk)
        #pragma unroll
        for (int j = 0; j < 8; ++j)
            ra[kk * 8 + j] = Rp[(size_t)kk * U + j];

    const int r = lane;
    #pragma unroll
    for (int k4 = 0; k4 < 32; k4 += 2) {
        // prefetch k4+1 into rb
        #pragma unroll
        for (int kk = 0; kk < 4; ++kk)
            #pragma unroll
            for (int j = 0; j < 8; ++j)
                rb[kk * 8 + j] = Rp[(size_t)((k4 + 1) * 4 + kk) * U + j];

        float4 av = a4[(r << 5) | (k4 ^ (r & 31))];
        #pragma unroll
        for (int j = 0; j < 8; ++j) {
            acc[j] = fmaf(av.x, ra[0 * 8 + j], acc[j]);
            acc[j] = fmaf(av.y, ra[1 * 8 + j], acc[j]);
            acc[j] = fmaf(av.z, ra[2 * 8 + j], acc[j]);
            acc[j] = fmaf(av.w, ra[3 * 8 + j], acc[j]);
        }

        // prefetch k4+2 into ra
        if (k4 + 2 < 32) {
            #pragma unroll
            for (int kk = 0; kk < 4; ++kk)
                #pragma unroll
                for (int j = 0; j < 8; ++j)
                    ra[kk * 8 + j] = Rp[(size_t)((k4 + 2) * 4 + kk) * U + j];
        }

        float4 av2 = a4[(r << 5) | ((k4 + 1) ^ (r & 31))];
        #pragma unroll
        for (int j = 0; j < 8; ++j) {
            acc[j] = fmaf(av2.x, rb[0 * 8 + j], acc[j]);
            acc[j] = fmaf(av2.y, rb[1 * 8 + j], acc[j]);
            acc[j] = fmaf(av2.z, rb[2 * 8 + j], acc[j]);
            acc[j] = fmaf(av2.w, rb[3 * 8 + j], acc[j]);
        }
    }

    HT* hp = h + ((size_t)(t0 + r) * B + b) * U + u0;
    store8(hp, acc);
}

// ---------------------------------------------------------------------------
// Kernel 2: recurrence. Grid 64 (one WG per batch row), 512 threads = 8 waves.
// Wave wv owns k-range [32wv, 32wv+32) AND reduces u' range [32wv, 32wv+32).
// Lane l owns u' columns {4l..4l+3} for the partial GEMV.
//
// fp16 dot2 path, all conversions RNE: W held as packed-fp16 k-pairs:
//   wh[j][m] = { W[k0+2m][4l+j], W[k0+2m+1][4l+j] }   (64 VGPRs, half of fp32)
// Per step the state is packed once per wave: DPP quad-perm xor1 brings the
// neighbor lane's s, RNE-pack {s[2m], s[2m+1]} on even lanes, and 16
// readlanes broadcast the packed pairs to SGPRs (was 32 readlanes). The GEMV
// is then 64 v_dot2_f32_f16 (2 MAC/lane/cy, f32 accumulate) instead of 128
// v_fma_f32 — halves the VALU-busy floor of the step.
// Per step: 1 DPP + 2 cvt + 1 pack + 16 v_readlane + 64 v_dot2, 1
// ds_write_b128 of partials, ONE raw barrier, 8 ds_read_b32 tree-reduced
// partials + tanh. h is pre-biased (hc[i] = h + bias) at chunk load. The
// reduced value tv sits in this wave's own lanes 0..31 — it IS next step's
// pack/readlane source, so no state write-back and no second barrier.
// Partials double-buffered (i&1).
// ---------------------------------------------------------------------------
template <typename HT>
__global__ __launch_bounds__(512, 2) void rnn_kernel(
    const HT* __restrict__ h,        // [T, B, U]
    const float* __restrict__ Wm,    // [U, U]
    const float* __restrict__ bias,  // [U]
    const float* __restrict__ x0,    // [U]
    float* __restrict__ out)         // [T, B, U]
{
    const int b    = blockIdx.x;
    const int tid  = threadIdx.x;
    const int l    = tid & 63;
    const int wv   = tid >> 6;       // 0..7
    const int k0   = wv << 5;        // wave's k-range / u'-reduction base

    __shared__ float p[2][8][256];   // 16 KB partials, double-buffered

    // W as packed fp16 k-pairs (RNE): wh[j][m] = {W[k0+2m][4l+j], W[k0+2m+1][4l+j]}
    h2 wh[4][16];
    {
        const float* wp = Wm + (size_t)k0 * U + 4 * l;
        #pragma unroll
        for (int m = 0; m < 16; ++m) {
            float4 r0 = *(const float4*)(wp + (size_t)(2 * m) * U);
            float4 r1 = *(const float4*)(wp + (size_t)(2 * m + 1) * U);
            wh[0][m] = pk_rne(r0.x, r1.x);
            wh[1][m] = pk_rne(r0.y, r1.y);
            wh[2][m] = pk_rne(r0.z, r1.z);
            wh[3][m] = pk_rne(r0.w, r1.w);
        }
    }

    const bool act = (l < 32);
    const int  u   = k0 + (l & 31);  // dup for lanes 32..63 (harmless)
    const float bv = bias[u];

    float tv = x0[u];                // s_new[k0 + (l&31)] lives here each step

    const size_t sT = (size_t)B * U;
    const HT* hp = h + (size_t)b * U + u;
    float* op = out + (size_t)b * U + u;

    float hc[CH], hn[CH], ob[CH];
    #pragma unroll
    for (int i = 0; i < CH; ++i) hc[i] = toF32(hp[(size_t)i * sT]) + bv;

    for (int tc = 0; tc < T; tc += CH) {
        // prefetch next chunk's h (not drained at raw barriers)
        if (tc + CH < T) {
            #pragma unroll
            for (int i = 0; i < CH; ++i)
                hn[i] = toF32(hp[(size_t)(tc + CH + i) * sT]);
        }
        // flush previous chunk's outputs
        if (tc > 0 && act) {
            #pragma unroll
            for (int i = 0; i < CH; ++i)
                op[(size_t)(tc - CH + i) * sT] = ob[i];
        }

        #pragma unroll
        for (int i = 0; i < CH; ++i) {
            // pack {s[2m], s[2m+1]} into fp16 pairs on even lanes:
            // DPP quad_perm [1,0,3,2] = xor1 neighbor, then RNE pack.
            float nb = __uint_as_float(__builtin_amdgcn_update_dpp(
                0, (int)__float_as_uint(tv), 0xB1 /*quad_perm 1,0,3,2*/,
                0xF, 0xF, true));
            unsigned int pku = h2bits(pk_rne(tv, nb));

            float a0 = 0.f, a1 = 0.f, a2 = 0.f, a3 = 0.f;
            #pragma unroll
            for (int m = 0; m < 16; ++m) {
                h2 sh = bits2h(__builtin_amdgcn_readlane(pku, 2 * m));
                a0 = fdot2(sh, wh[0][m], a0);
                a1 = fdot2(sh, wh[1][m], a1);
                a2 = fdot2(sh, wh[2][m], a2);
                a3 = fdot2(sh, wh[3][m], a3);
            }
            *(float4*)&p[i & 1][wv][4 * l] = make_float4(a0, a1, a2, a3);

            lds_barrier();           // ONE barrier per step (lgkm only)

            // tree-reduce 8 partials for u' = k0 + (l&31); lanes 32..63
            // duplicate (same-address LDS reads broadcast — no conflict)
            const float* pb = &p[i & 1][0][u];
            float q0 = pb[0 * 256], q1 = pb[1 * 256];
            float q2 = pb[2 * 256], q3 = pb[3 * 256];
            float q4 = pb[4 * 256], q5 = pb[5 * 256];
            float q6 = pb[6 * 256], q7 = pb[7 * 256];
            float red = ((q0 + q1) + (q2 + q3)) + ((q4 + q5) + (q6 + q7));

            float val = tanh_fast(red + hc[i]);   // hc pre-biased
            ob[i] = val;
            tv = val;                // next step's pack/readlane source
        }

        if (tc + CH < T) {
            #pragma unroll
            for (int i = 0; i < CH; ++i) hc[i] = hn[i] + bv;
        }
    }

    if (act) {
        #pragma unroll
        for (int i = 0; i < CH; ++i)
            op[(size_t)(T - CH + i) * sT] = ob[i];
    }
}

// ---------------------------------------------------------------------------
extern "C" void kernel_launch(void* const* d_in, const int* in_sizes, int n_in,
                              void* d_out, int out_size, void* d_ws, size_t ws_size,
                              hipStream_t stream) {
    const float* in   = (const float*)d_in[0];  // [B, T, F]
    const float* Rm   = (const float*)d_in[1];  // [F, U]
    const float* Wm   = (const float*)d_in[2];  // [U, U]
    const float* bias = (const float*)d_in[3];  // [U]
    const float* x0   = (const float*)d_in[4];  // [U]
    float* out = (float*)d_out;                 // [T, B, U]

    const size_t hElems = (size_t)T * B * U;
    dim3 pgrid(T / 64, U / 64, B);

    if (ws_size >= hElems * sizeof(float)) {
        float* h = (float*)d_ws;
        proj_kernel<float><<<pgrid, 512, 0, stream>>>(in, Rm, h);
        rnn_kernel<float><<<dim3(B), 512, 0, stream>>>(h, Wm, bias, x0, out);
    } else {
        __hip_bfloat16* h = (__hip_bfloat16*)d_ws;
        proj_kernel<__hip_bfloat16><<<pgrid, 512, 0, stream>>>(in, Rm, h);
        rnn_kernel<__hip_bfloat16><<<dim3(B), 512, 0, stream>>>(h, Wm, bias, x0, out);
    }
}